// Round 23
// baseline (286.558 us; speedup 1.0000x reference)
//
#include <hip/hip_runtime.h>
#include <math.h>

#define NN   65536
#define BB   256
#define NPGC 256
#define EE   1048576
#define DD   128
#define KK   128
#define NT2  32768
#define OUTD 12
#define BN_EPS 1e-5f
#define INV_N1 (1.f / 65536.f)
#define INV_N2 (1.f / 32768.f)

typedef __attribute__((ext_vector_type(8))) short bf16x8;
typedef __attribute__((ext_vector_type(4))) float f32x4;

__device__ __forceinline__ unsigned short bf16_rne(float v) {
    unsigned u = __float_as_uint(v);
    unsigned r = u + 0x7FFFu + ((u >> 16) & 1u);
    return (unsigned short)(r >> 16);
}
__device__ __forceinline__ float bfu(unsigned short h) {
    return __uint_as_float((unsigned)h << 16);
}

// ---------------- W prep: FRAG-MAJOR split layout ----------------
__global__ void k_prepw2(const float* __restrict__ Wg, unsigned short* __restrict__ wfH,
                         unsigned short* __restrict__ wfL) {
    int i = blockIdx.x * 256 + threadIdx.x;      // (l,c,kg,n): 5*4*4*128 = 10240
    if (i >= 10240) return;
    int n = i & 127, kg = (i >> 7) & 3, c = (i >> 9) & 3, l = i >> 11;
    size_t base = (size_t)((l * 16 + c * 4 + kg) * 128 + n) * 8;
#pragma unroll
    for (int j = 0; j < 8; ++j) {
        int k = c * 32 + kg * 8 + j;
        float v = Wg[l * 16384 + k * 128 + n];
        unsigned short hb = bf16_rne(v);
        wfH[base + j] = hb;
        wfL[base + j] = bf16_rne(v - bfu(hb));
    }
}

// 256-element inclusive scan, 2 barriers (in==out safe)
__device__ __forceinline__ void scan256(int t, const int* in, int* out, int* wtot) {
    int lane = t & 63, w = t >> 6;
    int v = (t < 256) ? in[t] : 0;
    int sv = v;
#pragma unroll
    for (int d = 1; d < 64; d <<= 1) {
        int u = __shfl_up(sv, d);
        if (lane >= d) sv += u;
    }
    if (t < 256 && lane == 63) wtot[w] = sv;
    __syncthreads();
    if (t < 256) {
        int off = 0;
        for (int i = 0; i < w; ++i) off += wtot[i];
        out[t] = sv + off;   // inclusive
    }
    __syncthreads();
}

// ---------------- The whole network: one graph per block, h resident in LDS ----------------
// R22 + dual node-chain gather (2x memory-level parallelism on the LDS latency chain).
__global__ __launch_bounds__(1024) void k_mega(
    const int* __restrict__ x, const int* __restrict__ ei,
    const float* __restrict__ emb,
    const unsigned short* __restrict__ wfH, const unsigned short* __restrict__ wfL,
    const float* __restrict__ bg, const float* __restrict__ gam,
    const float* __restrict__ bet, const float* __restrict__ epsArr,
    const float* __restrict__ tw, const float* __restrict__ oW,
    const float* __restrict__ ob, float* __restrict__ bnst,
    float* __restrict__ out)
{
    __shared__ __align__(16) unsigned char U[131072];      // h f32 OR bf16 A-tiles
    __shared__ __align__(16) unsigned short wS[2][4096];   // xr alias only (atom encoder)
    __shared__ __align__(4) unsigned char csr8[5120];      // padded-to-4 CSR
    __shared__ int offl[257];
    __shared__ int curl[256];
    __shared__ int sscan[256];
    __shared__ int wtot[4];
    __shared__ float score[256];
    __shared__ float scsh[256];
    __shared__ float wlds[128];
    __shared__ float pooled[128];
    __shared__ unsigned char newid[256];
    __shared__ unsigned char perml[128];
    __shared__ unsigned char flg[256];
    __shared__ float invn_s;

    float* hF = (float*)U;
    float2* hF2 = (float2*)U;
    unsigned* bcnt = (unsigned*)(bnst + 5 * 256);

    const int g = blockIdx.x;
    const int t = threadIdx.x;
    const int wv = t >> 6, l = t & 63;
    const int la = l & 15, kg = l >> 4;
    const int nbase = g * NPGC;
    const int* srcg = ei + g * 4096;
    const int* dstg = ei + EE + g * 4096;

    // ================= atom encoder =================
    {
        int* xr = (int*)wS;  // 2304 ints
        for (int i = t; i < NPGC * 9; i += 1024) xr[i] = x[nbase * 9 + i];
        __syncthreads();
        int n = t >> 2, cq = (t & 3) << 5;
        f32x4 a8[8] = {};
#pragma unroll
        for (int f = 0; f < 9; ++f) {
            const f32x4* ep = (const f32x4*)&emb[(size_t)((f << 7) + xr[n * 9 + f]) * DD + cq];
#pragma unroll
            for (int q = 0; q < 8; ++q) a8[q] += ep[q];
        }
        f32x4* hq = (f32x4*)&hF[n * DD + cq];
#pragma unroll
        for (int q = 0; q < 8; ++q) hq[q] = a8[q];
    }

    // ================= CSR1 (block-local, 4-aligned per node) =================
    for (int i = t; i < 256; i += 1024) curl[i] = 0;
    __syncthreads();
    for (int i = t; i < 4096; i += 1024) atomicAdd(&curl[dstg[i] - nbase], 1);
    __syncthreads();
    if (t < 256) sscan[t] = (curl[t] + 3) & ~3;
    __syncthreads();
    scan256(t, sscan, sscan, wtot);
    if (t < 256) offl[t] = sscan[t] - ((curl[t] + 3) & ~3);
    if (t == 255) offl[256] = sscan[255];
    for (int i = t; i < 256; i += 1024) curl[i] = 0;
    __syncthreads();
    for (int i = t; i < 4096; i += 1024) {
        int d = dstg[i] - nbase;
        int slot = offl[d] + atomicAdd(&curl[d], 1);
        csr8[slot] = (unsigned char)(srcg[i] - nbase);
    }
    __syncthreads();
    if (t < 256) {   // fill pad slots with self-index
        int cnt = curl[t], st = offl[t], en = offl[t + 1];
        for (int s2 = cnt; s2 < en - st; ++s2) csr8[st + s2] = (unsigned char)t;
    }
    __syncthreads();

    // ================= unified 5-layer loop =================
#pragma unroll 1
    for (int li = 0; li < 5; ++li) {
        // ---- between layers 2 and 3: top-k pool + gate + CSR2 ----
        if (li == 3) {
            if (t < DD) wlds[t] = tw[t];
            __syncthreads();
            if (t < 64) {
                float s = wlds[t] * wlds[t] + wlds[t + 64] * wlds[t + 64];
#pragma unroll
                for (int d = 32; d > 0; d >>= 1) s += __shfl_down(s, d);
                if (t == 0) invn_s = rsqrtf(s);
            }
            __syncthreads();
            {
                float wx = wlds[l * 2], wy = wlds[l * 2 + 1];
#pragma unroll 1
                for (int i = 0; i < 16; ++i) {
                    int node = wv * 16 + i;
                    float2 a = hF2[node * 64 + l];
                    float p = a.x * wx + a.y * wy;
                    p += __shfl_xor(p, 32); p += __shfl_xor(p, 16); p += __shfl_xor(p, 8);
                    p += __shfl_xor(p, 4);  p += __shfl_xor(p, 2);  p += __shfl_xor(p, 1);
                    if (l == 0) score[node] = p * invn_s;
                }
            }
            __syncthreads();
            if (t < 256) {
                float v = score[t];
                int rank = 0;
                for (int j = 0; j < 256; ++j) {
                    float u = score[j];
                    rank += (u > v) || (u == v && j < t);
                }
                int sel = rank < KK ? 1 : 0;
                flg[t] = (unsigned char)sel;
                sscan[t] = sel;
            }
            __syncthreads();
            scan256(t, sscan, sscan, wtot);
            if (t < 256) {
                if (flg[t]) {
                    int m = sscan[t] - 1;
                    newid[t] = (unsigned char)m;
                    perml[m] = (unsigned char)t;
                } else {
                    newid[t] = 0xFF;
                }
            }
            __syncthreads();
            {
                int m = t >> 3, cs = (t & 7) << 4;
                int src = perml[m];
                float tg = tanhf(score[src]);
                f32x4 gv[4];
#pragma unroll
                for (int q = 0; q < 4; ++q) {
                    gv[q] = ((const f32x4*)&hF[src * DD + cs])[q];
                    gv[q].x *= tg; gv[q].y *= tg; gv[q].z *= tg; gv[q].w *= tg;
                }
                __syncthreads();
#pragma unroll
                for (int q = 0; q < 4; ++q) ((f32x4*)&hF[m * DD + cs])[q] = gv[q];
            }
            __syncthreads();
            // CSR2 (kept edges, 4-aligned)
            for (int i = t; i < 256; i += 1024) curl[i] = 0;
            __syncthreads();
            for (int i = t; i < 4096; i += 1024) {
                int sn = newid[srcg[i] - nbase], dn = newid[dstg[i] - nbase];
                if (sn != 255 && dn != 255) atomicAdd(&curl[dn], 1);
            }
            __syncthreads();
            if (t < 256) sscan[t] = (curl[t] + 3) & ~3;
            __syncthreads();
            scan256(t, sscan, sscan, wtot);
            if (t < 256) offl[t] = sscan[t] - ((curl[t] + 3) & ~3);
            if (t == 255) offl[256] = sscan[255];
            for (int i = t; i < 256; i += 1024) curl[i] = 0;
            __syncthreads();
            for (int i = t; i < 4096; i += 1024) {
                int sn = newid[srcg[i] - nbase], dn = newid[dstg[i] - nbase];
                if (sn != 255 && dn != 255) {
                    int slot = offl[dn] + atomicAdd(&curl[dn], 1);
                    csr8[slot] = (unsigned char)sn;
                }
            }
            __syncthreads();
            if (t < 128) {
                int cnt = curl[t], st = offl[t], en = offl[t + 1];
                for (int s2 = cnt; s2 < en - st; ++s2) csr8[st + s2] = (unsigned char)t;
            }
            __syncthreads();
        }

        const int NODES = (li < 3) ? 256 : 128;
        const int npw = NODES >> 4;             // nodes per wave (16 or 8)
        const float invRows = (li < 3) ? INV_N1 : INV_N2;
        const int aBase = (li < 3) ? 0 : 65536;
        unsigned short* aH = (unsigned short*)(U + aBase);
        unsigned short* aL = (unsigned short*)(U + aBase + NODES * 256);
        const float opEps = 1.f + epsArr[li];

        // ---- gather: TWO interleaved node-chains (2x MLP on LDS latency) ----
        unsigned agH[16], agL[16];
#pragma unroll
        for (int pr = 0; pr < 8; ++pr) {
            if (pr < (npw >> 1)) {
                int n0 = wv * npw + pr * 2, n1 = n0 + 1;
                int s0 = offl[n0], e0 = offl[n0 + 1];
                int s1 = offl[n1], e1 = offl[n1 + 1];
                int p0 = (e0 - s0) - curl[n0];
                int p1 = (e1 - s1) - curl[n1];
                float2 a0 = hF2[n0 * 64 + l], a1 = hF2[n1 * 64 + l];
                float ax0 = a0.x * (opEps - (float)p0), ay0 = a0.y * (opEps - (float)p0);
                float ax1 = a1.x * (opEps - (float)p1), ay1 = a1.y * (opEps - (float)p1);
                int mA = (e0 - s0) >> 2, mB = (e1 - s1) >> 2;
                int mx = mA > mB ? mA : mB;
                unsigned pkA = (mA > 0) ? *(const unsigned*)&csr8[s0] : 0u;
                unsigned pkB = (mB > 0) ? *(const unsigned*)&csr8[s1] : 0u;
#pragma unroll 1
                for (int k = 0; k < mx; ++k) {
                    unsigned cA = pkA, cB = pkB;
                    if (k + 1 < mA) pkA = *(const unsigned*)&csr8[s0 + ((k + 1) << 2)];
                    if (k + 1 < mB) pkB = *(const unsigned*)&csr8[s1 + ((k + 1) << 2)];
                    if (k < mA) {
                        float2 v0 = hF2[(cA & 255u) * 64 + l];
                        float2 v1 = hF2[((cA >> 8) & 255u) * 64 + l];
                        float2 v2 = hF2[((cA >> 16) & 255u) * 64 + l];
                        float2 v3 = hF2[(cA >> 24) * 64 + l];
                        ax0 += v0.x + v1.x + v2.x + v3.x;
                        ay0 += v0.y + v1.y + v2.y + v3.y;
                    }
                    if (k < mB) {
                        float2 v0 = hF2[(cB & 255u) * 64 + l];
                        float2 v1 = hF2[((cB >> 8) & 255u) * 64 + l];
                        float2 v2 = hF2[((cB >> 16) & 255u) * 64 + l];
                        float2 v3 = hF2[(cB >> 24) * 64 + l];
                        ax1 += v0.x + v1.x + v2.x + v3.x;
                        ay1 += v0.y + v1.y + v2.y + v3.y;
                    }
                }
                unsigned hx0 = bf16_rne(ax0), hy0 = bf16_rne(ay0);
                agH[pr * 2] = hx0 | (hy0 << 16);
                agL[pr * 2] = (unsigned)bf16_rne(ax0 - bfu((unsigned short)hx0)) |
                              ((unsigned)bf16_rne(ay0 - bfu((unsigned short)hy0)) << 16);
                unsigned hx1 = bf16_rne(ax1), hy1 = bf16_rne(ay1);
                agH[pr * 2 + 1] = hx1 | (hy1 << 16);
                agL[pr * 2 + 1] = (unsigned)bf16_rne(ax1 - bfu((unsigned short)hx1)) |
                                  ((unsigned)bf16_rne(ay1 - bfu((unsigned short)hy1)) << 16);
            }
        }
        __syncthreads();   // all gathers done -> safe to overwrite h/A region
#pragma unroll
        for (int i = 0; i < 16; ++i) {
            if (i < npw) {
                int node = wv * npw + i;
                int idx = (node * DD + l * 2) ^ ((node & 7) << 3);
                *(unsigned*)&aH[idx] = agH[i];
                *(unsigned*)&aL[idx] = agL[i];
            }
        }
        __syncthreads();   // A-tiles visible to all waves

        // ---- MFMA: A from LDS, B frag-major from global (R22) ----
        const unsigned short* WHf = wfH + li * 16384;
        const unsigned short* WLf = wfL + li * 16384;
        f32x4 acc[8] = {};
        const int rowa = wv * 16 + la;
        const int aXor = (rowa & 7) << 3;
        const bool act = wv < npw;
        if (act) {
#pragma unroll 1
            for (int c = 0; c < 4; ++c) {
                int ai = (rowa * DD + c * 32 + kg * 8) ^ aXor;
                bf16x8 ah = *(const bf16x8*)&aH[ai];
                bf16x8 al = *(const bf16x8*)&aL[ai];
                const unsigned short* wb = WHf + (size_t)((c * 4 + kg) * 128) * 8;
                const unsigned short* wl2 = WLf + (size_t)((c * 4 + kg) * 128) * 8;
#pragma unroll
                for (int gi = 0; gi < 8; ++gi) {
                    size_t wi = (size_t)(gi * 16 + la) * 8;
                    bf16x8 bh = *(const bf16x8*)&wb[wi];
                    bf16x8 bl = *(const bf16x8*)&wl2[wi];
                    acc[gi] = __builtin_amdgcn_mfma_f32_16x16x32_bf16(ah, bh, acc[gi], 0, 0, 0);
                    acc[gi] = __builtin_amdgcn_mfma_f32_16x16x32_bf16(ah, bl, acc[gi], 0, 0, 0);
                    acc[gi] = __builtin_amdgcn_mfma_f32_16x16x32_bf16(al, bh, acc[gi], 0, 0, 0);
                }
            }
        }
        __syncthreads();   // all A-tile reads done -> partials may overwrite region

        // ---- bias + BN partial stats ----
        float* partS = (float*)(U + aBase);
        float* partQ = (float*)(U + aBase + 8192);
        if (act) {
#pragma unroll
            for (int gi = 0; gi < 8; ++gi) {
                int col = gi * 16 + la;
                float bv = bg[li * DD + col];
                float s = 0.f, q = 0.f;
#pragma unroll
                for (int r = 0; r < 4; ++r) {
                    float o = acc[gi][r] + bv;
                    acc[gi][r] = o;
                    s += o; q += o * o;
                }
                s += __shfl_xor(s, 16); s += __shfl_xor(s, 32);
                q += __shfl_xor(q, 16); q += __shfl_xor(q, 32);
                if (kg == 0) { partS[wv * DD + col] = s; partQ[wv * DD + col] = q; }
            }
        }
        __syncthreads();
        if (t < DD) {
            float s = 0.f, q = 0.f;
            for (int i = 0; i < npw; ++i) { s += partS[i * DD + t]; q += partQ[i * DD + t]; }
            atomicAdd(&bnst[li * 256 + t], s);
            atomicAdd(&bnst[li * 256 + DD + t], q);
        }
        // ---- grid barrier (monotonic counter) ----
        __syncthreads();
        if (t == 0) {
            __threadfence();
            atomicAdd(bcnt, 1u);
            unsigned tgt = 256u * (unsigned)(li + 1);
            while (__hip_atomic_load(bcnt, __ATOMIC_RELAXED, __HIP_MEMORY_SCOPE_AGENT) < tgt)
                __builtin_amdgcn_s_sleep(2);
            __threadfence();
        }
        __syncthreads();
        if (t < DD) {
            float s = __hip_atomic_load(&bnst[li * 256 + t], __ATOMIC_RELAXED, __HIP_MEMORY_SCOPE_AGENT);
            float q = __hip_atomic_load(&bnst[li * 256 + DD + t], __ATOMIC_RELAXED, __HIP_MEMORY_SCOPE_AGENT);
            float mu = s * invRows;
            float var = q * invRows - mu * mu;
            float istd = rsqrtf(var + BN_EPS);
            float ga = gam[li * DD + t], be = bet[li * DD + t];
            scsh[t] = ga * istd;
            scsh[DD + t] = be - mu * ga * istd;
        }
        __syncthreads();
        // ---- BN apply + ReLU -> h ----
        if (act) {
#pragma unroll
            for (int gi = 0; gi < 8; ++gi) {
                int col = gi * 16 + la;
                float sc = scsh[col], sh = scsh[DD + col];
#pragma unroll
                for (int r = 0; r < 4; ++r) {
                    int row = wv * 16 + kg * 4 + r;
                    hF[row * DD + col] = fmaxf(acc[gi][r] * sc + sh, 0.f);
                }
            }
        }
        __syncthreads();
    }

    // ================= mean-pool + head + sigmoid =================
    {
        float* partP = (float*)(U + 65536);   // h rows 128..255: dead in phase 2
        int c = t & 127, grp = t >> 7;
        float s = 0.f;
        for (int r = grp * 16; r < grp * 16 + 16; ++r) s += hF[r * DD + c];
        partP[grp * DD + c] = s;
        float* oWl = (float*)(U + 65536 + 8192);
        for (int i = t; i < DD * OUTD; i += 1024) oWl[i] = oW[i];
        __syncthreads();
        if (t < DD) {
            float s2 = 0.f;
#pragma unroll
            for (int i = 0; i < 8; ++i) s2 += partP[i * DD + t];
            pooled[t] = s2 * (1.f / (float)KK);
        }
        __syncthreads();
        if (t < OUTD) {
            float o = ob[t];
            for (int k = 0; k < DD; ++k) o += pooled[k] * oWl[k * OUTD + t];
            out[g * OUTD + t] = 1.f / (1.f + expf(-o));
        }
    }
}

extern "C" void kernel_launch(void* const* d_in, const int* in_sizes, int n_in,
                              void* d_out, int out_size, void* d_ws, size_t ws_size,
                              hipStream_t stream) {
    const int*   x        = (const int*)d_in[0];
    const int*   ei       = (const int*)d_in[1];
    const float* atom_emb = (const float*)d_in[4];
    const float* convW    = (const float*)d_in[6];
    const float* convb    = (const float*)d_in[7];
    const float* gam      = (const float*)d_in[8];
    const float* bet      = (const float*)d_in[9];
    const float* eps      = (const float*)d_in[10];
    const float* tw       = (const float*)d_in[11];
    const float* oW       = (const float*)d_in[12];
    const float* ob       = (const float*)d_in[13];
    float* outp = (float*)d_out;

    char* p = (char*)d_ws;
    float* bnst = (float*)p;                   p += (size_t)5 * 256 * 4 + 16;  // + barrier counter
    unsigned short* wfH = (unsigned short*)p;  p += (size_t)5 * 16 * 128 * 8 * 2;
    unsigned short* wfL = (unsigned short*)p;  p += (size_t)5 * 16 * 128 * 8 * 2;
    if ((size_t)(p - (char*)d_ws) > ws_size) return;

    hipMemsetAsync(bnst, 0, (size_t)5 * 256 * 4 + 16, stream);
    k_prepw2<<<40, 256, 0, stream>>>(convW, wfH, wfL);

    void* args[] = {
        (void*)&x, (void*)&ei, (void*)&atom_emb, (void*)&wfH, (void*)&wfL,
        (void*)&convb, (void*)&gam, (void*)&bet, (void*)&eps, (void*)&tw,
        (void*)&oW, (void*)&ob, (void*)&bnst, (void*)&outp
    };
    hipLaunchCooperativeKernel((void*)k_mega, dim3(BB), dim3(1024), args, 0, stream);
}

// Round 24
// 282.025 us; speedup vs baseline: 1.0161x; 1.0161x over previous
//
#include <hip/hip_runtime.h>
#include <math.h>

#define NN   65536
#define BB   256
#define NPGC 256
#define EE   1048576
#define DD   128
#define KK   128
#define NT2  32768
#define OUTD 12
#define BN_EPS 1e-5f
#define INV_N1 (1.f / 65536.f)
#define INV_N2 (1.f / 32768.f)

typedef __attribute__((ext_vector_type(8))) short bf16x8;
typedef __attribute__((ext_vector_type(4))) float f32x4;

__device__ __forceinline__ unsigned short bf16_rne(float v) {
    unsigned u = __float_as_uint(v);
    unsigned r = u + 0x7FFFu + ((u >> 16) & 1u);
    return (unsigned short)(r >> 16);
}
__device__ __forceinline__ float bfu(unsigned short h) {
    return __uint_as_float((unsigned)h << 16);
}

// ---------------- W prep: FRAG-MAJOR split layout ----------------
// wf[((l*16 + c*4 + kg)*128 + n)*8 + j] = split(W[l][c*32+kg*8+j][n])
__global__ void k_prepw2(const float* __restrict__ Wg, unsigned short* __restrict__ wfH,
                         unsigned short* __restrict__ wfL) {
    int i = blockIdx.x * 256 + threadIdx.x;      // (l,c,kg,n): 5*4*4*128 = 10240
    if (i >= 10240) return;
    int n = i & 127, kg = (i >> 7) & 3, c = (i >> 9) & 3, l = i >> 11;
    size_t base = (size_t)((l * 16 + c * 4 + kg) * 128 + n) * 8;
#pragma unroll
    for (int j = 0; j < 8; ++j) {
        int k = c * 32 + kg * 8 + j;
        float v = Wg[l * 16384 + k * 128 + n];
        unsigned short hb = bf16_rne(v);
        wfH[base + j] = hb;
        wfL[base + j] = bf16_rne(v - bfu(hb));
    }
}

// 256-element inclusive scan, 2 barriers (in==out safe)
__device__ __forceinline__ void scan256(int t, const int* in, int* out, int* wtot) {
    int lane = t & 63, w = t >> 6;
    int v = (t < 256) ? in[t] : 0;
    int sv = v;
#pragma unroll
    for (int d = 1; d < 64; d <<= 1) {
        int u = __shfl_up(sv, d);
        if (lane >= d) sv += u;
    }
    if (t < 256 && lane == 63) wtot[w] = sv;
    __syncthreads();
    if (t < 256) {
        int off = 0;
        for (int i = 0; i < w; ++i) off += wtot[i];
        out[t] = sv + off;   // inclusive
    }
    __syncthreads();
}

// ---------------- The whole network: one graph per block, h resident in LDS ----------------
// Final: R13 skeleton + frag-major W direct-from-global MFMA (R22, best measured: 282us).
__global__ __launch_bounds__(1024) void k_mega(
    const int* __restrict__ x, const int* __restrict__ ei,
    const float* __restrict__ emb,
    const unsigned short* __restrict__ wfH, const unsigned short* __restrict__ wfL,
    const float* __restrict__ bg, const float* __restrict__ gam,
    const float* __restrict__ bet, const float* __restrict__ epsArr,
    const float* __restrict__ tw, const float* __restrict__ oW,
    const float* __restrict__ ob, float* __restrict__ bnst,
    float* __restrict__ out)
{
    __shared__ __align__(16) unsigned char U[131072];      // h f32 OR bf16 A-tiles
    __shared__ __align__(16) unsigned short wS[2][4096];   // xr alias only (atom encoder)
    __shared__ __align__(4) unsigned char csr8[5120];      // padded-to-4 CSR
    __shared__ int offl[257];
    __shared__ int curl[256];
    __shared__ int sscan[256];
    __shared__ int wtot[4];
    __shared__ float score[256];
    __shared__ float scsh[256];
    __shared__ float wlds[128];
    __shared__ float pooled[128];
    __shared__ unsigned char newid[256];
    __shared__ unsigned char perml[128];
    __shared__ unsigned char flg[256];
    __shared__ float invn_s;

    float* hF = (float*)U;
    float2* hF2 = (float2*)U;
    unsigned* bcnt = (unsigned*)(bnst + 5 * 256);

    const int g = blockIdx.x;
    const int t = threadIdx.x;
    const int wv = t >> 6, l = t & 63;
    const int la = l & 15, kg = l >> 4;
    const int nbase = g * NPGC;
    const int* srcg = ei + g * 4096;
    const int* dstg = ei + EE + g * 4096;

    // ================= atom encoder =================
    {
        int* xr = (int*)wS;  // 2304 ints
        for (int i = t; i < NPGC * 9; i += 1024) xr[i] = x[nbase * 9 + i];
        __syncthreads();
        int n = t >> 2, cq = (t & 3) << 5;
        f32x4 a8[8] = {};
#pragma unroll
        for (int f = 0; f < 9; ++f) {
            const f32x4* ep = (const f32x4*)&emb[(size_t)((f << 7) + xr[n * 9 + f]) * DD + cq];
#pragma unroll
            for (int q = 0; q < 8; ++q) a8[q] += ep[q];
        }
        f32x4* hq = (f32x4*)&hF[n * DD + cq];
#pragma unroll
        for (int q = 0; q < 8; ++q) hq[q] = a8[q];
    }

    // ================= CSR1 (block-local, 4-aligned per node) =================
    for (int i = t; i < 256; i += 1024) curl[i] = 0;
    __syncthreads();
    for (int i = t; i < 4096; i += 1024) atomicAdd(&curl[dstg[i] - nbase], 1);
    __syncthreads();
    if (t < 256) sscan[t] = (curl[t] + 3) & ~3;
    __syncthreads();
    scan256(t, sscan, sscan, wtot);
    if (t < 256) offl[t] = sscan[t] - ((curl[t] + 3) & ~3);
    if (t == 255) offl[256] = sscan[255];
    for (int i = t; i < 256; i += 1024) curl[i] = 0;
    __syncthreads();
    for (int i = t; i < 4096; i += 1024) {
        int d = dstg[i] - nbase;
        int slot = offl[d] + atomicAdd(&curl[d], 1);
        csr8[slot] = (unsigned char)(srcg[i] - nbase);
    }
    __syncthreads();
    if (t < 256) {   // fill pad slots with self-index
        int cnt = curl[t], st = offl[t], en = offl[t + 1];
        for (int s2 = cnt; s2 < en - st; ++s2) csr8[st + s2] = (unsigned char)t;
    }
    __syncthreads();

    // ================= unified 5-layer loop =================
#pragma unroll 1
    for (int li = 0; li < 5; ++li) {
        // ---- between layers 2 and 3: top-k pool + gate + CSR2 ----
        if (li == 3) {
            if (t < DD) wlds[t] = tw[t];
            __syncthreads();
            if (t < 64) {
                float s = wlds[t] * wlds[t] + wlds[t + 64] * wlds[t + 64];
#pragma unroll
                for (int d = 32; d > 0; d >>= 1) s += __shfl_down(s, d);
                if (t == 0) invn_s = rsqrtf(s);
            }
            __syncthreads();
            {
                float wx = wlds[l * 2], wy = wlds[l * 2 + 1];
#pragma unroll 1
                for (int i = 0; i < 16; ++i) {
                    int node = wv * 16 + i;
                    float2 a = hF2[node * 64 + l];
                    float p = a.x * wx + a.y * wy;
                    p += __shfl_xor(p, 32); p += __shfl_xor(p, 16); p += __shfl_xor(p, 8);
                    p += __shfl_xor(p, 4);  p += __shfl_xor(p, 2);  p += __shfl_xor(p, 1);
                    if (l == 0) score[node] = p * invn_s;
                }
            }
            __syncthreads();
            if (t < 256) {
                float v = score[t];
                int rank = 0;
                for (int j = 0; j < 256; ++j) {
                    float u = score[j];
                    rank += (u > v) || (u == v && j < t);
                }
                int sel = rank < KK ? 1 : 0;
                flg[t] = (unsigned char)sel;
                sscan[t] = sel;
            }
            __syncthreads();
            scan256(t, sscan, sscan, wtot);
            if (t < 256) {
                if (flg[t]) {
                    int m = sscan[t] - 1;
                    newid[t] = (unsigned char)m;
                    perml[m] = (unsigned char)t;
                } else {
                    newid[t] = 0xFF;
                }
            }
            __syncthreads();
            {
                int m = t >> 3, cs = (t & 7) << 4;
                int src = perml[m];
                float tg = tanhf(score[src]);
                f32x4 gv[4];
#pragma unroll
                for (int q = 0; q < 4; ++q) {
                    gv[q] = ((const f32x4*)&hF[src * DD + cs])[q];
                    gv[q].x *= tg; gv[q].y *= tg; gv[q].z *= tg; gv[q].w *= tg;
                }
                __syncthreads();
#pragma unroll
                for (int q = 0; q < 4; ++q) ((f32x4*)&hF[m * DD + cs])[q] = gv[q];
            }
            __syncthreads();
            // CSR2 (kept edges, 4-aligned)
            for (int i = t; i < 256; i += 1024) curl[i] = 0;
            __syncthreads();
            for (int i = t; i < 4096; i += 1024) {
                int sn = newid[srcg[i] - nbase], dn = newid[dstg[i] - nbase];
                if (sn != 255 && dn != 255) atomicAdd(&curl[dn], 1);
            }
            __syncthreads();
            if (t < 256) sscan[t] = (curl[t] + 3) & ~3;
            __syncthreads();
            scan256(t, sscan, sscan, wtot);
            if (t < 256) offl[t] = sscan[t] - ((curl[t] + 3) & ~3);
            if (t == 255) offl[256] = sscan[255];
            for (int i = t; i < 256; i += 1024) curl[i] = 0;
            __syncthreads();
            for (int i = t; i < 4096; i += 1024) {
                int sn = newid[srcg[i] - nbase], dn = newid[dstg[i] - nbase];
                if (sn != 255 && dn != 255) {
                    int slot = offl[dn] + atomicAdd(&curl[dn], 1);
                    csr8[slot] = (unsigned char)sn;
                }
            }
            __syncthreads();
            if (t < 128) {
                int cnt = curl[t], st = offl[t], en = offl[t + 1];
                for (int s2 = cnt; s2 < en - st; ++s2) csr8[st + s2] = (unsigned char)t;
            }
            __syncthreads();
        }

        const int NODES = (li < 3) ? 256 : 128;
        const int npw = NODES >> 4;             // nodes per wave (16 or 8)
        const float invRows = (li < 3) ? INV_N1 : INV_N2;
        const int aBase = (li < 3) ? 0 : 65536; // A-tiles overwrite dead h region
        unsigned short* aH = (unsigned short*)(U + aBase);
        unsigned short* aL = (unsigned short*)(U + aBase + NODES * 256);
        const float opEps = 1.f + epsArr[li];

        // ---- gather (padded-u32 CSR, single chain, results packed to 2 u32/node) ----
        unsigned agH[16], agL[16];
#pragma unroll
        for (int i = 0; i < 16; ++i) {
            if (i < npw) {
                int node = wv * npw + i;
                int st = offl[node], en = offl[node + 1];
                int pad = (en - st) - curl[node];
                float2 a = hF2[node * 64 + l];
                float ax = a.x * (opEps - (float)pad);
                float ay = a.y * (opEps - (float)pad);
                int m = (en - st) >> 2;
                unsigned pk = (m > 0) ? *(const unsigned*)&csr8[st] : 0u;
#pragma unroll 1
                for (int k = 0; k < m; ++k) {
                    unsigned c = pk;
                    if (k + 1 < m) pk = *(const unsigned*)&csr8[st + ((k + 1) << 2)];
                    float2 v0 = hF2[(c & 255u) * 64 + l];
                    float2 v1 = hF2[((c >> 8) & 255u) * 64 + l];
                    float2 v2 = hF2[((c >> 16) & 255u) * 64 + l];
                    float2 v3 = hF2[(c >> 24) * 64 + l];
                    ax += v0.x + v1.x + v2.x + v3.x;
                    ay += v0.y + v1.y + v2.y + v3.y;
                }
                unsigned hx = bf16_rne(ax), hy = bf16_rne(ay);
                float rx = ax - __uint_as_float(hx << 16);
                float ry = ay - __uint_as_float(hy << 16);
                agH[i] = hx | (hy << 16);
                agL[i] = (unsigned)bf16_rne(rx) | ((unsigned)bf16_rne(ry) << 16);
            }
        }
        __syncthreads();   // all gathers done -> safe to overwrite h/A region
#pragma unroll
        for (int i = 0; i < 16; ++i) {
            if (i < npw) {
                int node = wv * npw + i;
                int idx = (node * DD + l * 2) ^ ((node & 7) << 3);
                *(unsigned*)&aH[idx] = agH[i];
                *(unsigned*)&aL[idx] = agL[i];
            }
        }
        __syncthreads();   // A-tiles visible to all waves

        // ---- MFMA: A from LDS, B frag-major from global (coalesced 16B/lane, L1/L2-hot) ----
        const unsigned short* WHf = wfH + li * 16384;
        const unsigned short* WLf = wfL + li * 16384;
        f32x4 acc[8] = {};
        const int rowa = wv * 16 + la;
        const int aXor = (rowa & 7) << 3;
        const bool act = wv < npw;
        if (act) {
#pragma unroll 1
            for (int c = 0; c < 4; ++c) {
                int ai = (rowa * DD + c * 32 + kg * 8) ^ aXor;
                bf16x8 ah = *(const bf16x8*)&aH[ai];
                bf16x8 al = *(const bf16x8*)&aL[ai];
                const unsigned short* wb = WHf + (size_t)((c * 4 + kg) * 128) * 8;
                const unsigned short* wl2 = WLf + (size_t)((c * 4 + kg) * 128) * 8;
#pragma unroll
                for (int gi = 0; gi < 8; ++gi) {
                    size_t wi = (size_t)(gi * 16 + la) * 8;
                    bf16x8 bh = *(const bf16x8*)&wb[wi];
                    bf16x8 bl = *(const bf16x8*)&wl2[wi];
                    acc[gi] = __builtin_amdgcn_mfma_f32_16x16x32_bf16(ah, bh, acc[gi], 0, 0, 0);
                    acc[gi] = __builtin_amdgcn_mfma_f32_16x16x32_bf16(ah, bl, acc[gi], 0, 0, 0);
                    acc[gi] = __builtin_amdgcn_mfma_f32_16x16x32_bf16(al, bh, acc[gi], 0, 0, 0);
                }
            }
        }
        __syncthreads();   // all A-tile reads done -> partials may overwrite region

        // ---- bias + BN partial stats ----
        float* partS = (float*)(U + aBase);
        float* partQ = (float*)(U + aBase + 8192);
        if (act) {
#pragma unroll
            for (int gi = 0; gi < 8; ++gi) {
                int col = gi * 16 + la;
                float bv = bg[li * DD + col];
                float s = 0.f, q = 0.f;
#pragma unroll
                for (int r = 0; r < 4; ++r) {
                    float o = acc[gi][r] + bv;
                    acc[gi][r] = o;
                    s += o; q += o * o;
                }
                s += __shfl_xor(s, 16); s += __shfl_xor(s, 32);
                q += __shfl_xor(q, 16); q += __shfl_xor(q, 32);
                if (kg == 0) { partS[wv * DD + col] = s; partQ[wv * DD + col] = q; }
            }
        }
        __syncthreads();
        if (t < DD) {
            float s = 0.f, q = 0.f;
            for (int i = 0; i < npw; ++i) { s += partS[i * DD + t]; q += partQ[i * DD + t]; }
            atomicAdd(&bnst[li * 256 + t], s);
            atomicAdd(&bnst[li * 256 + DD + t], q);
        }
        // ---- grid barrier (monotonic counter) ----
        __syncthreads();
        if (t == 0) {
            __threadfence();
            atomicAdd(bcnt, 1u);
            unsigned tgt = 256u * (unsigned)(li + 1);
            while (__hip_atomic_load(bcnt, __ATOMIC_RELAXED, __HIP_MEMORY_SCOPE_AGENT) < tgt)
                __builtin_amdgcn_s_sleep(2);
            __threadfence();
        }
        __syncthreads();
        if (t < DD) {
            float s = __hip_atomic_load(&bnst[li * 256 + t], __ATOMIC_RELAXED, __HIP_MEMORY_SCOPE_AGENT);
            float q = __hip_atomic_load(&bnst[li * 256 + DD + t], __ATOMIC_RELAXED, __HIP_MEMORY_SCOPE_AGENT);
            float mu = s * invRows;
            float var = q * invRows - mu * mu;
            float istd = rsqrtf(var + BN_EPS);
            float ga = gam[li * DD + t], be = bet[li * DD + t];
            scsh[t] = ga * istd;
            scsh[DD + t] = be - mu * ga * istd;
        }
        __syncthreads();
        // ---- BN apply + ReLU -> h ----
        if (act) {
#pragma unroll
            for (int gi = 0; gi < 8; ++gi) {
                int col = gi * 16 + la;
                float sc = scsh[col], sh = scsh[DD + col];
#pragma unroll
                for (int r = 0; r < 4; ++r) {
                    int row = wv * 16 + kg * 4 + r;
                    hF[row * DD + col] = fmaxf(acc[gi][r] * sc + sh, 0.f);
                }
            }
        }
        __syncthreads();
    }

    // ================= mean-pool + head + sigmoid =================
    {
        float* partP = (float*)(U + 65536);   // h rows 128..255: dead in phase 2
        int c = t & 127, grp = t >> 7;
        float s = 0.f;
        for (int r = grp * 16; r < grp * 16 + 16; ++r) s += hF[r * DD + c];
        partP[grp * DD + c] = s;
        float* oWl = (float*)(U + 65536 + 8192);
        for (int i = t; i < DD * OUTD; i += 1024) oWl[i] = oW[i];
        __syncthreads();
        if (t < DD) {
            float s2 = 0.f;
#pragma unroll
            for (int i = 0; i < 8; ++i) s2 += partP[i * DD + t];
            pooled[t] = s2 * (1.f / (float)KK);
        }
        __syncthreads();
        if (t < OUTD) {
            float o = ob[t];
            for (int k = 0; k < DD; ++k) o += pooled[k] * oWl[k * OUTD + t];
            out[g * OUTD + t] = 1.f / (1.f + expf(-o));
        }
    }
}

extern "C" void kernel_launch(void* const* d_in, const int* in_sizes, int n_in,
                              void* d_out, int out_size, void* d_ws, size_t ws_size,
                              hipStream_t stream) {
    const int*   x        = (const int*)d_in[0];
    const int*   ei       = (const int*)d_in[1];
    const float* atom_emb = (const float*)d_in[4];
    const float* convW    = (const float*)d_in[6];
    const float* convb    = (const float*)d_in[7];
    const float* gam      = (const float*)d_in[8];
    const float* bet      = (const float*)d_in[9];
    const float* eps      = (const float*)d_in[10];
    const float* tw       = (const float*)d_in[11];
    const float* oW       = (const float*)d_in[12];
    const float* ob       = (const float*)d_in[13];
    float* outp = (float*)d_out;

    char* p = (char*)d_ws;
    float* bnst = (float*)p;                   p += (size_t)5 * 256 * 4 + 16;  // + barrier counter
    unsigned short* wfH = (unsigned short*)p;  p += (size_t)5 * 16 * 128 * 8 * 2;
    unsigned short* wfL = (unsigned short*)p;  p += (size_t)5 * 16 * 128 * 8 * 2;
    if ((size_t)(p - (char*)d_ws) > ws_size) return;

    hipMemsetAsync(bnst, 0, (size_t)5 * 256 * 4 + 16, stream);
    k_prepw2<<<40, 256, 0, stream>>>(convW, wfH, wfL);

    void* args[] = {
        (void*)&x, (void*)&ei, (void*)&atom_emb, (void*)&wfH, (void*)&wfL,
        (void*)&convb, (void*)&gam, (void*)&bet, (void*)&eps, (void*)&tw,
        (void*)&oW, (void*)&ob, (void*)&bnst, (void*)&outp
    };
    hipLaunchCooperativeKernel((void*)k_mega, dim3(BB), dim3(1024), args, 0, stream);
}